// Round 12
// baseline (282.527 us; speedup 1.0000x reference)
//
#include <hip/hip_runtime.h>
#include <hip/hip_fp16.h>
#include <utility>
#include <type_traits>

// =====================================================================
// 16-qubit, batch-256 statevector simulator.  R20.
//
// R19 post-mortem: scratch ELIMINATED (WRITE 91MB->16KB, VGPR 116) but
// dur only 257->247 and VALUBusy stuck ~52% -> dep-chain theory mostly
// wrong.  New accounting: VALU issue ~128us; LDS pipe ~138us (4700 LDS
// ops/thread: sg4 granule churn + ds_bpermute shfls + xbuf staging,
// shared across 8 waves/CU).  LDS pipe is the co-bottleneck.
//
// R20 (one variable): STORED-BIT PERMUTATION.  Gate cost class = which
// fields (local[0:7]/lane[7:13]/wave[13:16]) its pair mask touches.
// The field assignment was arbitrary (identity).  Relabeling stored
// bits by a permutation is FREE (init reads itab through it; gm/gc/meas
// masks permute) and reclassifies gates.  Constexpr search: (1) wave
// triple minimizing #masks touching it (C(16,3)=560); (2) local 7-of-13
// maximizing #masks fully contained (1716 combos).  ~300K steps.
//
// Predicted: >=8 gates reclassified -> dur 247 -> 205-230us, VALUBusy
// 52->55-60%; null -> masks dense -> pivot to DPP-lane-exchange +
// direct-partner sg4 reads + NSR=104.
// =====================================================================

constexpr int NSR  = 96;   // register-resident amplitudes per thread
constexpr int NGRR = 24;   // reg granules (4 amps each)
constexpr int NGL  = 8;    // LDS granules
constexpr int NG   = 32;   // total granules

// ---------------- compile-time GF(2) matrices ----------------
struct M16 { unsigned r[16]; };

constexpr M16 ident() { M16 m{}; for (int i = 0; i < 16; ++i) m.r[i] = 1u << i; return m; }

constexpr M16 ringm(int s) {
  M16 m = ident();
  for (int i = 15; i >= 0; --i) {
    int pc = 15 - i;
    int pt = 15 - ((i + s) & 15);
    m.r[pt] ^= m.r[pc];
  }
  return m;
}

constexpr M16 mmul(M16 A, M16 B) {
  M16 C{};
  for (int p = 0; p < 16; ++p) {
    unsigned v = 0;
    for (int q = 0; q < 16; ++q) if ((A.r[p] >> q) & 1u) v ^= B.r[q];
    C.r[p] = v;
  }
  return C;
}

constexpr M16 minv(M16 A) {
  M16 I = ident();
  for (int col = 0; col < 16; ++col) {
    int piv = -1;
    for (int row = col; row < 16; ++row) if ((A.r[row] >> col) & 1u) { piv = row; break; }
    unsigned t = A.r[piv]; A.r[piv] = A.r[col]; A.r[col] = t;
    t = I.r[piv]; I.r[piv] = I.r[col]; I.r[col] = t;
    for (int row = 0; row < 16; ++row)
      if (row != col && ((A.r[row] >> col) & 1u)) { A.r[row] ^= A.r[col]; I.r[row] ^= I.r[col]; }
  }
  return I;
}

constexpr bool meq(M16 a, M16 b) { for (int i = 0; i < 16; ++i) if (a.r[i] != b.r[i]) return false; return true; }
constexpr unsigned colmask(M16 P, int b) { unsigned m = 0; for (int p = 0; p < 16; ++p) m |= ((P.r[p] >> b) & 1u) << p; return m; }
constexpr int popc16(unsigned x) { int c = 0; for (int i = 0; i < 16; ++i) c += (x >> i) & 1; return c; }
constexpr int topbit_pow(unsigned x) { int b = 0; for (int i = 0; i < 16; ++i) if ((x >> i) & 1) b = i; return 1 << b; }

struct Tables { unsigned gm[64]; unsigned gc[64]; unsigned meas[16]; };

constexpr Tables make_tables() {
  Tables T{};
  M16 R1 = ringm(1), R2 = ringm(2);
  M16 P0 = R1;
  M16 P1 = mmul(R1, R1);
  M16 P2 = mmul(P1, R2);
  M16 P3 = mmul(P2, R2);
  M16 P[4] = { P0, P1, P2, P3 };
  for (int k = 0; k < 4; ++k) {
    M16 A = minv(P[k]);
    for (int b = 0; b < 16; ++b) {
      T.gm[k * 16 + b] = colmask(P[k], b);
      T.gc[k * 16 + b] = A.r[b];
    }
  }
  M16 A5 = minv(P[3]);
  for (int w = 0; w < 16; ++w) T.meas[w] = A5.r[15 - w];
  return T;
}

constexpr Tables TB_RAW = make_tables();

// ---------------- stored-bit permutation search ----------------
// ASSIGN.a[p] = original bit position placed at new stored position p.
// positions 0..6 = local field, 7..12 = lane field, 13..15 = wave field.
struct Assign { int a[16]; };

constexpr Assign make_assign() {
  // stage 1: wave triple minimizing # masks touching it (wave gates)
  int bx = 13, by = 14, bz = 15, bestw = 1 << 30;
  for (int x = 0; x < 16; ++x)
    for (int y = x + 1; y < 16; ++y)
      for (int z = y + 1; z < 16; ++z) {
        const unsigned W = (1u << x) | (1u << y) | (1u << z);
        int cnt = 0;
        for (int g = 0; g < 64; ++g) if (TB_RAW.gm[g] & W) ++cnt;
        if (cnt < bestw) { bestw = cnt; bx = x; by = y; bz = z; }
      }
  const unsigned Wf = (1u << bx) | (1u << by) | (1u << bz);
  // stage 2: local 7 (of remaining 13) maximizing # masks fully inside
  int rem[13] = {}; int nr = 0;
  for (int b = 0; b < 16; ++b) if (!((Wf >> b) & 1)) rem[nr++] = b;
  unsigned bestL = 0; int bestc = -1;
  for (unsigned s = 0; s < (1u << 13); ++s) {
    if (popc16(s) != 7) continue;
    unsigned Lm = 0;
    for (int i = 0; i < 13; ++i) if ((s >> i) & 1) Lm |= 1u << rem[i];
    int cnt = 0;
    for (int g = 0; g < 64; ++g) if ((TB_RAW.gm[g] & ~Lm) == 0) ++cnt;
    if (cnt > bestc) { bestc = cnt; bestL = Lm; }
  }
  Assign A{}; int pl = 0, pn = 7, pw = 13;
  for (int b = 0; b < 16; ++b) {
    if ((bestL >> b) & 1)      A.a[pl++] = b;
    else if ((Wf >> b) & 1)    A.a[pw++] = b;
    else                       A.a[pn++] = b;
  }
  return A;
}

constexpr Assign AS = make_assign();

constexpr bool assign_ok() {
  unsigned seen = 0;
  for (int p = 0; p < 16; ++p) {
    if (AS.a[p] < 0 || AS.a[p] > 15) return false;
    seen |= 1u << AS.a[p];
  }
  return seen == 0xFFFFu;
}
static_assert(assign_ok(), "ASSIGN not a permutation");

constexpr unsigned permute_mask(unsigned m) {
  unsigned r = 0;
  for (int p = 0; p < 16; ++p) r |= ((m >> AS.a[p]) & 1u) << p;
  return r;
}

constexpr Tables permute_tables() {
  Tables T{};
  for (int g = 0; g < 64; ++g) { T.gm[g] = permute_mask(TB_RAW.gm[g]); T.gc[g] = permute_mask(TB_RAW.gc[g]); }
  for (int w = 0; w < 16; ++w) T.meas[w] = permute_mask(TB_RAW.meas[w]);
  return T;
}

constexpr Tables TB = permute_tables();

constexpr bool check_tables() {
  for (int g = 0; g < 64; ++g) if ((popc16(TB.gm[g] & TB.gc[g]) & 1) != 1) return false;
  if (!meq(mmul(ringm(1), minv(ringm(1))), ident())) return false;
  if (!meq(mmul(ringm(2), minv(ringm(2))), ident())) return false;
  return true;
}
static_assert(check_tables(), "GF(2) table inconsistency");
static_assert(sizeof(__half2) == 4, "half2 size");

// ---------------- small device helpers ----------------
template<int N, int I = 0, typename F>
__device__ __forceinline__ void sfor(F&& f) {
  if constexpr (I < N) {
    f(std::integral_constant<int, I>{});
    sfor<N, I + 1>(static_cast<F&&>(f));
  }
}

__device__ __forceinline__ int h2i(__half2 v) { return __builtin_bit_cast(int, v); }
__device__ __forceinline__ __half2 i2h(int v) { return __builtin_bit_cast(__half2, v); }
__device__ __forceinline__ unsigned h2u(__half2 v) { return __builtin_bit_cast(unsigned, v); }
__device__ __forceinline__ __half2 u2h(unsigned v) { return __builtin_bit_cast(__half2, v); }

// ---- packed-fp16 complex update, TWO independent chains per asm block ----
__device__ __forceinline__ void upd2(__half2& x0r, __half2& x1r,
                                     __half2 xp0_, __half2 xp1_,
                                     __half2 c0_, __half2 c1a_, __half2 c1b_,
                                     __half2 c2a_, __half2 c2b_, __half2 c3_) {
  const unsigned x0 = h2u(x0r), x1 = h2u(x1r), xp0 = h2u(xp0_), xp1 = h2u(xp1_);
  const unsigned c0 = h2u(c0_), c1a = h2u(c1a_), c1b = h2u(c1b_),
                 c2a = h2u(c2a_), c2b = h2u(c2b_), c3 = h2u(c3_);
  unsigned y0, y1;
  asm("v_pk_mul_f16 %0, %2, %3\n\t"
      "v_pk_mul_f16 %1, %2, %4\n\t"
      "v_pk_fma_f16 %0, %5, %3, %0 op_sel:[0,1,0] op_sel_hi:[1,0,1]\n\t"
      "v_pk_fma_f16 %1, %6, %4, %1 op_sel:[0,1,0] op_sel_hi:[1,0,1]\n\t"
      "v_pk_fma_f16 %0, %7, %9, %0\n\t"
      "v_pk_fma_f16 %1, %8, %10, %1\n\t"
      "v_pk_fma_f16 %0, %11, %9, %0 op_sel:[0,1,0] op_sel_hi:[1,0,1]\n\t"
      "v_pk_fma_f16 %1, %11, %10, %1 op_sel:[0,1,0] op_sel_hi:[1,0,1]"
      : "=&v"(y0), "=&v"(y1)
      : "v"(c0), "v"(x0), "v"(x1), "v"(c1a), "v"(c1b),
        "v"(c2a), "v"(c2b), "v"(xp0), "v"(xp1), "v"(c3));
  x0r = u2h(y0); x1r = u2h(y1);
}

// partner-value fetch: lx==0 -> same thread; else shfl_xor across lanes
template<int lx>
__device__ __forceinline__ __half2 pget(__half2 v) {
  if constexpr (lx == 0) return v;
  else return i2h(__shfl_xor(h2i(v), lx, 64));
}

// SU(2) for U = Ry(c) Rz(b) Ry(a):  U = [[al, -conj(be)], [be, conj(al)]]
__device__ __forceinline__ void su2_coeffs(float a, float b, float c,
                                           float& are, float& aim, float& bre, float& bim) {
  float sapc, capc, samc, camc, sb, cb;
  __sincosf((a + c) * 0.5f, &sapc, &capc);
  __sincosf((a - c) * 0.5f, &samc, &camc);
  __sincosf(b * 0.5f, &sb, &cb);
  are = cb * capc;
  aim = -sb * camc;
  bre = cb * sapc;
  bim = sb * samc;
}

__device__ __forceinline__ unsigned pkh2(float lo, float hi) {
  return h2u(__floats2half2_rn(lo, hi));
}

__device__ __forceinline__ float2 cmulf(float2 a, float vr, float vi) {
  return make_float2(a.x * vr - a.y * vi, a.x * vi + a.y * vr);
}

// ---------------- virtual granules ----------------
template<int G>
__device__ __forceinline__ void vg_load(const __half2 (&S)[NSR], const uint4* sg4,
                                        unsigned tid, __half2 (&a)[4]) {
  if constexpr (G < NGRR) {
    a[0] = S[4*G]; a[1] = S[4*G+1]; a[2] = S[4*G+2]; a[3] = S[4*G+3];
  } else {
    const uint4 v = sg4[(G - NGRR) * 512 + tid];
    a[0] = u2h(v.x); a[1] = u2h(v.y); a[2] = u2h(v.z); a[3] = u2h(v.w);
  }
}
template<int G>
__device__ __forceinline__ void vg_store(__half2 (&S)[NSR], uint4* sg4,
                                         unsigned tid, const __half2 (&a)[4]) {
  if constexpr (G < NGRR) {
    S[4*G] = a[0]; S[4*G+1] = a[1]; S[4*G+2] = a[2]; S[4*G+3] = a[3];
  } else {
    sg4[(G - NGRR) * 512 + tid] = make_uint4(h2u(a[0]), h2u(a[1]), h2u(a[2]), h2u(a[3]));
  }
}
template<int G>
__device__ __forceinline__ uint4 vg_pack(const __half2 (&S)[NSR], const uint4* sg4, unsigned tid) {
  if constexpr (G < NGRR)
    return make_uint4(h2u(S[4*G]), h2u(S[4*G+1]), h2u(S[4*G+2]), h2u(S[4*G+3]));
  else
    return sg4[(G - NGRR) * 512 + tid];
}

// update granule G from staged partner uint4 (elem map e^me); 2 upd2 blocks
template<int G, int me, unsigned cm>
__device__ __forceinline__ void vg_upd(__half2 (&S)[NSR], uint4* sg4, unsigned tid, uint4 pv,
                                       __half2 c0, __half2 c1p, __half2 c1n,
                                       __half2 c2p, __half2 c2n, __half2 c3) {
  const unsigned q[4] = { pv.x, pv.y, pv.z, pv.w };
  __half2 a[4]; vg_load<G>(S, sg4, tid, a);
  constexpr int t0 = popc16(cm & (unsigned)(4*G+0)) & 1;
  constexpr int t1 = popc16(cm & (unsigned)(4*G+1)) & 1;
  constexpr int t2 = popc16(cm & (unsigned)(4*G+2)) & 1;
  constexpr int t3 = popc16(cm & (unsigned)(4*G+3)) & 1;
  upd2(a[0], a[1], u2h(q[0^me]), u2h(q[1^me]),
       c0, t0?c1n:c1p, t1?c1n:c1p, t0?c2n:c2p, t1?c2n:c2p, c3);
  upd2(a[2], a[3], u2h(q[2^me]), u2h(q[3^me]),
       c0, t2?c1n:c1p, t3?c1n:c1p, t2?c2n:c2p, t3?c2n:c2p, c3);
  vg_store<G>(S, sg4, tid, a);
}

// ---------------- generalized gate application ----------------
// j = (tid << 7) | L;  L in [0,128): 96 reg amps + 32 LDS amps.
template<int G>
__device__ __forceinline__ void apply_gate(__half2 (&S)[NSR], unsigned tid,
                                           const uint4* __restrict__ ctabg,
                                           uint4* sg4, uint4* xbuf4) {
  constexpr unsigned m  = TB.gm[G];
  constexpr unsigned c  = TB.gc[G];
  constexpr unsigned mL = m & 127u;   // local-bit part (7 bits)
  constexpr unsigned mT = m >> 7;     // thread-bit part (lane 0..5, wave 6..8)
  constexpr unsigned mW = m >> 13;    // wave part (3 bits)

  const uint4 cc = ctabg[G];
  const unsigned fm = (__popc((c >> 7) & tid) & 1u) ? 0x80008000u : 0u;
  const unsigned c1u = cc.y ^ fm, c2u = cc.z ^ fm;
  const __half2 c0 = u2h(cc.x), c3 = u2h(cc.w);
  const __half2 c1p = u2h(c1u), c1n = u2h(c1u ^ 0x80008000u);
  const __half2 c2p = u2h(c2u), c2n = u2h(c2u ^ 0x80008000u);

  if constexpr (mW == 0u) {
    // ============ in-thread / lane-crossing (generic granule walk) ============
    constexpr int lx = (int)mT;       // 0 -> pure local; else shfl distance
    if constexpr (mL == 0u) {
      // self-position pair across lanes (lx != 0)
      sfor<NG>([&](auto gg) {
        constexpr int g = decltype(gg)::value;
        __half2 a[4]; vg_load<g>(S, sg4, tid, a);
        const __half2 p0 = pget<lx>(a[0]), p1 = pget<lx>(a[1]);
        const __half2 p2 = pget<lx>(a[2]), p3 = pget<lx>(a[3]);
        constexpr int t0 = popc16(c & (unsigned)(4*g+0)) & 1;
        constexpr int t1 = popc16(c & (unsigned)(4*g+1)) & 1;
        constexpr int t2 = popc16(c & (unsigned)(4*g+2)) & 1;
        constexpr int t3 = popc16(c & (unsigned)(4*g+3)) & 1;
        upd2(a[0], a[1], p0, p1, c0, t0?c1n:c1p, t1?c1n:c1p, t0?c2n:c2p, t1?c2n:c2p, c3);
        upd2(a[2], a[3], p2, p3, c0, t2?c1n:c1p, t3?c1n:c1p, t2?c2n:c2p, t3?c2n:c2p, c3);
        vg_store<g>(S, sg4, tid, a);
      });
    } else if constexpr ((mL >> 2) == 0u) {
      // within-granule pairs (mL in 1..3): one upd2 per pair
      constexpr int tb = topbit_pow(mL);
      sfor<NG>([&](auto gg) {
        constexpr int g = decltype(gg)::value;
        __half2 a[4]; vg_load<g>(S, sg4, tid, a);
        sfor<4>([&](auto ee) {
          constexpr int e = decltype(ee)::value;
          if constexpr ((e & tb) == 0) {
            constexpr int e1 = e ^ (int)mL;
            constexpr int t0 = popc16(c & (unsigned)(4*g+e)) & 1;
            constexpr int t1 = popc16(c & (unsigned)(4*g+e1)) & 1;
            const __half2 x0 = a[e], x1 = a[e1];
            upd2(a[e], a[e1], pget<lx>(x1), pget<lx>(x0),
                 c0, t0?c1n:c1p, t1?c1n:c1p, t0?c2n:c2p, t1?c2n:c2p, c3);
          }
        });
        vg_store<g>(S, sg4, tid, a);
      });
    } else {
      // granule pairs (gA, gB = gA ^ hg); reg/LDS/mixed handled by vg_*
      constexpr int hg = (int)(mL >> 2);
      constexpr int tb = topbit_pow((unsigned)hg);
      constexpr int me = (int)(mL & 3u);
      sfor<NG>([&](auto ga_) {
        constexpr int gA = decltype(ga_)::value;
        if constexpr ((gA & tb) == 0) {
          constexpr int gB = gA ^ hg;
          __half2 a[4], b4[4];
          vg_load<gA>(S, sg4, tid, a); vg_load<gB>(S, sg4, tid, b4);
          sfor<4>([&](auto ee) {
            constexpr int e  = decltype(ee)::value;
            constexpr int e2 = e ^ me;
            constexpr int t0 = popc16(c & (unsigned)(4*gA+e)) & 1;
            constexpr int t1 = popc16(c & (unsigned)(4*gB+e2)) & 1;
            const __half2 x0 = a[e], x1 = b4[e2];
            upd2(a[e], b4[e2], pget<lx>(x1), pget<lx>(x0),
                 c0, t0?c1n:c1p, t1?c1n:c1p, t0?c2n:c2p, t1?c2n:c2p, c3);
          });
          vg_store<gA>(S, sg4, tid, a); vg_store<gB>(S, sg4, tid, b4);
        }
      });
    }
  } else {
    // ============ wave-crossing: xbuf rounds (8 slots, stride-9 pad) ============
    const unsigned ptid = tid ^ (unsigned)mT;
    constexpr unsigned hG = mL >> 2;          // granule xor (5 bits)
    constexpr int      me = (int)(mL & 3u);
    if constexpr (hG == 0u) {
      // partner in same granule: 4 rounds of 8 consecutive granules
      sfor<4>([&](auto rr) {
        constexpr int r = decltype(rr)::value;
        sfor<8>([&](auto kk) {
          constexpr int k = decltype(kk)::value;
          xbuf4[tid * 9u + (unsigned)k] = vg_pack<r * 8 + k>(S, sg4, tid);
        });
        __syncthreads();
        sfor<8>([&](auto kk) {
          constexpr int k = decltype(kk)::value;
          const uint4 pv = xbuf4[ptid * 9u + (unsigned)k];
          vg_upd<r * 8 + k, me, c>(S, sg4, tid, pv, c0, c1p, c1n, c2p, c2n, c3);
        });
        __syncthreads();
      });
    } else {
      // granule pairs (gA, gB = gA ^ hG): 4 rounds of 4 pairs
      constexpr int tbG = topbit_pow(hG);
      sfor<4>([&](auto rr) {
        constexpr int r = decltype(rr)::value;
        sfor<4>([&](auto kk) {
          constexpr int k  = decltype(kk)::value;
          constexpr int i  = r * 4 + k;
          constexpr int gA = ((i & ~(tbG - 1)) << 1) | (i & (tbG - 1));
          constexpr int gB = gA ^ (int)hG;
          xbuf4[tid * 9u + (unsigned)k]       = vg_pack<gA>(S, sg4, tid);
          xbuf4[tid * 9u + (unsigned)(4 + k)] = vg_pack<gB>(S, sg4, tid);
        });
        __syncthreads();
        sfor<4>([&](auto kk) {
          constexpr int k  = decltype(kk)::value;
          constexpr int i  = r * 4 + k;
          constexpr int gA = ((i & ~(tbG - 1)) << 1) | (i & (tbG - 1));
          constexpr int gB = gA ^ (int)hG;
          const uint4 pvB = xbuf4[ptid * 9u + (unsigned)(4 + k)];
          const uint4 pvA = xbuf4[ptid * 9u + (unsigned)k];
          vg_upd<gA, me, c>(S, sg4, tid, pvB, c0, c1p, c1n, c2p, c2n, c3);
          vg_upd<gB, me, c>(S, sg4, tid, pvA, c0, c1p, c1n, c2p, c2n, c3);
        });
        __syncthreads();
      });
    }
  }
}

// ---------------- coefficient prekernel (batch-independent) ----------------
__global__ void ctab_build(const float* __restrict__ weight, uint4* __restrict__ ctabg) {
  const int g = (int)threadIdx.x;   // 64 threads
  const int k = g >> 4;             // 0..3 -> layers 2..5
  const int bb = g & 15;
  const int w = 15 - bb;            // wire for this logical bit
  const int base = 48 * (k + 1) + 3 * w;
  float are, aim, bre, bim;
  su2_coeffs(weight[base], weight[base + 1], weight[base + 2], are, aim, bre, bim);
  ctabg[g] = make_uint4(pkh2(are, are), pkh2(-aim, aim),
                        pkh2(-bre, -bre), pkh2(-bim, bim));
}

// ---------------- main kernel ----------------
__global__ __attribute__((amdgpu_flat_work_group_size(512, 512)))
void qcir_kernel(const float* __restrict__ inputs, const float* __restrict__ weight,
                 float* __restrict__ out, const uint4* __restrict__ ctabg) {
  __shared__ uint4  sg4[NGL * 512];  // 64 KB LDS-resident state
  __shared__ uint4  xbuf4[512 * 9];  // 73.7 KB exchange staging (stride-9 pad)
  __shared__ float4 itab[16];
  __shared__ float  red[8 * 16];

  const unsigned tid = threadIdx.x;   // 9 bits
  const unsigned b   = blockIdx.x;

  // ---- itab: per-wire (al,be) after encoding + layer 1 ----
  if (tid < 16) {
    const int w = (int)tid;
    const float a = weight[3 * w] + inputs[b * 16 + w];
    float are, aim, bre, bim;
    su2_coeffs(a, weight[3 * w + 1], weight[3 * w + 2], are, aim, bre, bim);
    itab[w] = make_float4(are, aim, bre, bim);
  }
  __syncthreads();

  // ---- init: product state after encoding + layer 1  (A1 = I) ----
  // stored bit p corresponds to original bit AS.a[p] -> wire 15 - AS.a[p]
  __half2 S[NSR];
  float2 P = make_float2(1.f, 0.f);
  sfor<9>([&](auto pp) {                          // thread bits: stored 7..15
    constexpr int p = 7 + decltype(pp)::value;
    const int bit = (int)(tid >> (p - 7)) & 1;
    const float4 t = itab[15 - AS.a[p]];
    P = cmulf(P, bit ? t.z : t.x, bit ? t.w : t.y);
  });
  sfor<16>([&](auto hh) {
    constexpr int h = decltype(hh)::value;        // chunk of 8: stored bits 3..6
    float2 ph = P;
    sfor<4>([&](auto qq) {
      constexpr int q   = decltype(qq)::value;
      constexpr int bit = (h >> q) & 1;
      const float4 t = itab[15 - AS.a[3 + q]];
      if constexpr (bit) ph = cmulf(ph, t.z, t.w); else ph = cmulf(ph, t.x, t.y);
    });
    if constexpr (h < 12) {
      sfor<8>([&](auto ll) {
        constexpr int l = decltype(ll)::value;
        float2 pl = ph;
        sfor<3>([&](auto qq) {
          constexpr int q   = decltype(qq)::value;
          constexpr int bit = (l >> q) & 1;
          const float4 t = itab[15 - AS.a[q]];
          if constexpr (bit) pl = cmulf(pl, t.z, t.w); else pl = cmulf(pl, t.x, t.y);
        });
        S[h * 8 + l] = __floats2half2_rn(pl.x, pl.y);
      });
    } else {
      __half2 a0[4], a1[4];
      sfor<8>([&](auto ll) {
        constexpr int l = decltype(ll)::value;
        float2 pl = ph;
        sfor<3>([&](auto qq) {
          constexpr int q   = decltype(qq)::value;
          constexpr int bit = (l >> q) & 1;
          const float4 t = itab[15 - AS.a[q]];
          if constexpr (bit) pl = cmulf(pl, t.z, t.w); else pl = cmulf(pl, t.x, t.y);
        });
        const __half2 v = __floats2half2_rn(pl.x, pl.y);
        if constexpr (l < 4) a0[l] = v; else a1[l - 4] = v;
      });
      sg4[(2 * (h - 12)) * 512 + tid]     = make_uint4(h2u(a0[0]), h2u(a0[1]), h2u(a0[2]), h2u(a0[3]));
      sg4[(2 * (h - 12) + 1) * 512 + tid] = make_uint4(h2u(a1[0]), h2u(a1[1]), h2u(a1[2]), h2u(a1[3]));
    }
  });
  __syncthreads();

  // ---- layers 2..5: 64 generalized gates (rings virtualized) ----
  sfor<64>([&](auto gg) { apply_gate<decltype(gg)::value>(S, tid, ctabg, sg4, xbuf4); });

  // ---- measurement: <Z_w> in 2 passes of 8 outputs ----
  sfor<2>([&](auto hf_) {
    constexpr int hf = decltype(hf_)::value;
    float acc[8];
    sfor<8>([&](auto ww) { acc[decltype(ww)::value] = 0.f; });
    sfor<NSR>([&](auto ll) {
      constexpr int L = decltype(ll)::value;
      const float re = __low2float(S[L]);
      const float im = __high2float(S[L]);
      const float p = re * re + im * im;
      sfor<8>([&](auto w8) {
        constexpr int w = hf * 8 + decltype(w8)::value;
        constexpr int t = popc16(TB.meas[w] & 127u & (unsigned)L) & 1;
        if constexpr (t) acc[decltype(w8)::value] -= p; else acc[decltype(w8)::value] += p;
      });
    });
    sfor<NGL>([&](auto gg) {
      constexpr int g = decltype(gg)::value;
      const uint4 v = sg4[g * 512 + tid];
      const unsigned q[4] = { v.x, v.y, v.z, v.w };
      sfor<4>([&](auto ee) {
        constexpr int e = decltype(ee)::value;
        constexpr int L = NSR + g * 4 + e;
        const __half2 av = u2h(q[e]);
        const float re = __low2float(av);
        const float im = __high2float(av);
        const float p = re * re + im * im;
        sfor<8>([&](auto w8) {
          constexpr int w = hf * 8 + decltype(w8)::value;
          constexpr int t = popc16(TB.meas[w] & 127u & (unsigned)L) & 1;
          if constexpr (t) acc[decltype(w8)::value] -= p; else acc[decltype(w8)::value] += p;
        });
      });
    });
    sfor<8>([&](auto w8) {
      constexpr int w = hf * 8 + decltype(w8)::value;
      const unsigned fw = __popc((TB.meas[w] >> 7) & tid) & 1u;
      float z = fw ? -acc[decltype(w8)::value] : acc[decltype(w8)::value];
#pragma unroll
      for (int d = 1; d < 64; d <<= 1) z += __shfl_xor(z, d, 64);
      if ((tid & 63u) == 0u) red[(tid >> 6) * 16 + w] = z;
    });
  });
  __syncthreads();
  if (tid < 16) {
    float s = 0.f;
#pragma unroll
    for (int v = 0; v < 8; ++v) s += red[v * 16 + tid];
    out[b * 16 + tid] = 4.f * s;
  }
}

// ---------------- launcher ----------------
extern "C" void kernel_launch(void* const* d_in, const int* in_sizes, int n_in,
                              void* d_out, int out_size, void* d_ws, size_t ws_size,
                              hipStream_t stream) {
  const float* inputs = (const float*)d_in[0];   // (B, 16) f32
  const float* weight = (const float*)d_in[1];   // (240,)  f32
  float* out = (float*)d_out;                    // (B, 16) f32
  const int B = in_sizes[0] / 16;
  uint4* ctabg = reinterpret_cast<uint4*>(d_ws); // 1 KB of workspace
  ctab_build<<<1, 64, 0, stream>>>(weight, ctabg);
  qcir_kernel<<<B, 512, 0, stream>>>(inputs, weight, out, ctabg);
}

// Round 13
// 272.997 us; speedup vs baseline: 1.0349x; 1.0349x over previous
//
#include <hip/hip_runtime.h>
#include <hip/hip_fp16.h>
#include <utility>
#include <type_traits>

// =====================================================================
// 16-qubit, batch-256 statevector simulator.  R21.
//
// R20 post-mortem: stored-bit permutation NULL (252 vs R19 244-251;
// identity layout already near-optimal for dense ring masks).  Plateau
// accounting: VALU ~126us (floor 55), LDS pipe ~75us, stalls ~50us.
//
// R21: (1) revert permutation (R19 identity tables = measured best);
// (2) NSR 96 -> 104 (26 reg + 6 LDS granules): sg4 LDS traffic -25%.
// VGPR prediction ~124 <= 128 (R19's upd2 form measured 116).
// DECISIVE counter: WRITE_SIZE stays ~16KB = no spill; if it jumps,
// margin was too thin -> revert to 96.
//
// Predicted: dur 244-252 -> 230-245us if sg4 traffic couples to the
// critical path; null -> stall-structural plateau (setprio next, or
// declare practical ceiling of the VALU-based structure).
// =====================================================================

constexpr int NSR  = 104;  // register-resident amplitudes per thread
constexpr int NGRR = 26;   // reg granules (4 amps each)
constexpr int NGL  = 6;    // LDS granules
constexpr int NG   = 32;   // total granules

// ---------------- compile-time GF(2) matrices ----------------
struct M16 { unsigned r[16]; };

constexpr M16 ident() { M16 m{}; for (int i = 0; i < 16; ++i) m.r[i] = 1u << i; return m; }

constexpr M16 ringm(int s) {
  M16 m = ident();
  for (int i = 15; i >= 0; --i) {
    int pc = 15 - i;
    int pt = 15 - ((i + s) & 15);
    m.r[pt] ^= m.r[pc];
  }
  return m;
}

constexpr M16 mmul(M16 A, M16 B) {
  M16 C{};
  for (int p = 0; p < 16; ++p) {
    unsigned v = 0;
    for (int q = 0; q < 16; ++q) if ((A.r[p] >> q) & 1u) v ^= B.r[q];
    C.r[p] = v;
  }
  return C;
}

constexpr M16 minv(M16 A) {
  M16 I = ident();
  for (int col = 0; col < 16; ++col) {
    int piv = -1;
    for (int row = col; row < 16; ++row) if ((A.r[row] >> col) & 1u) { piv = row; break; }
    unsigned t = A.r[piv]; A.r[piv] = A.r[col]; A.r[col] = t;
    t = I.r[piv]; I.r[piv] = I.r[col]; I.r[col] = t;
    for (int row = 0; row < 16; ++row)
      if (row != col && ((A.r[row] >> col) & 1u)) { A.r[row] ^= A.r[col]; I.r[row] ^= I.r[col]; }
  }
  return I;
}

constexpr bool meq(M16 a, M16 b) { for (int i = 0; i < 16; ++i) if (a.r[i] != b.r[i]) return false; return true; }
constexpr unsigned colmask(M16 P, int b) { unsigned m = 0; for (int p = 0; p < 16; ++p) m |= ((P.r[p] >> b) & 1u) << p; return m; }
constexpr int popc16(unsigned x) { int c = 0; for (int i = 0; i < 16; ++i) c += (x >> i) & 1; return c; }
constexpr int topbit_pow(unsigned x) { int b = 0; for (int i = 0; i < 16; ++i) if ((x >> i) & 1) b = i; return 1 << b; }

struct Tables { unsigned gm[64]; unsigned gc[64]; unsigned meas[16]; };

constexpr Tables make_tables() {
  Tables T{};
  M16 R1 = ringm(1), R2 = ringm(2);
  M16 P0 = R1;
  M16 P1 = mmul(R1, R1);
  M16 P2 = mmul(P1, R2);
  M16 P3 = mmul(P2, R2);
  M16 P[4] = { P0, P1, P2, P3 };
  for (int k = 0; k < 4; ++k) {
    M16 A = minv(P[k]);
    for (int b = 0; b < 16; ++b) {
      T.gm[k * 16 + b] = colmask(P[k], b);
      T.gc[k * 16 + b] = A.r[b];
    }
  }
  M16 A5 = minv(P[3]);
  for (int w = 0; w < 16; ++w) T.meas[w] = A5.r[15 - w];
  return T;
}

constexpr Tables TB = make_tables();

constexpr bool check_tables() {
  for (int g = 0; g < 64; ++g) if ((popc16(TB.gm[g] & TB.gc[g]) & 1) != 1) return false;
  if (!meq(mmul(ringm(1), minv(ringm(1))), ident())) return false;
  if (!meq(mmul(ringm(2), minv(ringm(2))), ident())) return false;
  return true;
}
static_assert(check_tables(), "GF(2) table inconsistency");
static_assert(sizeof(__half2) == 4, "half2 size");

// ---------------- small device helpers ----------------
template<int N, int I = 0, typename F>
__device__ __forceinline__ void sfor(F&& f) {
  if constexpr (I < N) {
    f(std::integral_constant<int, I>{});
    sfor<N, I + 1>(static_cast<F&&>(f));
  }
}

__device__ __forceinline__ int h2i(__half2 v) { return __builtin_bit_cast(int, v); }
__device__ __forceinline__ __half2 i2h(int v) { return __builtin_bit_cast(__half2, v); }
__device__ __forceinline__ unsigned h2u(__half2 v) { return __builtin_bit_cast(unsigned, v); }
__device__ __forceinline__ __half2 u2h(unsigned v) { return __builtin_bit_cast(__half2, v); }

// ---- packed-fp16 complex update, TWO independent chains per asm block ----
// chain i: yi = c0*xi + c1i*swap(xi) + c2i*xpi + c3*swap(xpi)
// swap(src1) = op_sel:[0,1,0] op_sel_hi:[1,0,1].  Role negation is
// pre-folded into the c1i/c2i operands by the caller (sign-XOR copies).
__device__ __forceinline__ void upd2(__half2& x0r, __half2& x1r,
                                     __half2 xp0_, __half2 xp1_,
                                     __half2 c0_, __half2 c1a_, __half2 c1b_,
                                     __half2 c2a_, __half2 c2b_, __half2 c3_) {
  const unsigned x0 = h2u(x0r), x1 = h2u(x1r), xp0 = h2u(xp0_), xp1 = h2u(xp1_);
  const unsigned c0 = h2u(c0_), c1a = h2u(c1a_), c1b = h2u(c1b_),
                 c2a = h2u(c2a_), c2b = h2u(c2b_), c3 = h2u(c3_);
  unsigned y0, y1;
  asm("v_pk_mul_f16 %0, %2, %3\n\t"
      "v_pk_mul_f16 %1, %2, %4\n\t"
      "v_pk_fma_f16 %0, %5, %3, %0 op_sel:[0,1,0] op_sel_hi:[1,0,1]\n\t"
      "v_pk_fma_f16 %1, %6, %4, %1 op_sel:[0,1,0] op_sel_hi:[1,0,1]\n\t"
      "v_pk_fma_f16 %0, %7, %9, %0\n\t"
      "v_pk_fma_f16 %1, %8, %10, %1\n\t"
      "v_pk_fma_f16 %0, %11, %9, %0 op_sel:[0,1,0] op_sel_hi:[1,0,1]\n\t"
      "v_pk_fma_f16 %1, %11, %10, %1 op_sel:[0,1,0] op_sel_hi:[1,0,1]"
      : "=&v"(y0), "=&v"(y1)
      : "v"(c0), "v"(x0), "v"(x1), "v"(c1a), "v"(c1b),
        "v"(c2a), "v"(c2b), "v"(xp0), "v"(xp1), "v"(c3));
  x0r = u2h(y0); x1r = u2h(y1);
}

// partner-value fetch: lx==0 -> same thread; else shfl_xor across lanes
template<int lx>
__device__ __forceinline__ __half2 pget(__half2 v) {
  if constexpr (lx == 0) return v;
  else return i2h(__shfl_xor(h2i(v), lx, 64));
}

// SU(2) for U = Ry(c) Rz(b) Ry(a):  U = [[al, -conj(be)], [be, conj(al)]]
__device__ __forceinline__ void su2_coeffs(float a, float b, float c,
                                           float& are, float& aim, float& bre, float& bim) {
  float sapc, capc, samc, camc, sb, cb;
  __sincosf((a + c) * 0.5f, &sapc, &capc);
  __sincosf((a - c) * 0.5f, &samc, &camc);
  __sincosf(b * 0.5f, &sb, &cb);
  are = cb * capc;
  aim = -sb * camc;
  bre = cb * sapc;
  bim = sb * samc;
}

__device__ __forceinline__ unsigned pkh2(float lo, float hi) {
  return h2u(__floats2half2_rn(lo, hi));
}

__device__ __forceinline__ float2 cmulf(float2 a, float vr, float vi) {
  return make_float2(a.x * vr - a.y * vi, a.x * vi + a.y * vr);
}

// ---------------- virtual granules ----------------
// granule G in [0,32): amps 4G..4G+3.  G < NGRR -> registers; else LDS
// sg4[(G-NGRR)*512 + tid].
template<int G>
__device__ __forceinline__ void vg_load(const __half2 (&S)[NSR], const uint4* sg4,
                                        unsigned tid, __half2 (&a)[4]) {
  if constexpr (G < NGRR) {
    a[0] = S[4*G]; a[1] = S[4*G+1]; a[2] = S[4*G+2]; a[3] = S[4*G+3];
  } else {
    const uint4 v = sg4[(G - NGRR) * 512 + tid];
    a[0] = u2h(v.x); a[1] = u2h(v.y); a[2] = u2h(v.z); a[3] = u2h(v.w);
  }
}
template<int G>
__device__ __forceinline__ void vg_store(__half2 (&S)[NSR], uint4* sg4,
                                         unsigned tid, const __half2 (&a)[4]) {
  if constexpr (G < NGRR) {
    S[4*G] = a[0]; S[4*G+1] = a[1]; S[4*G+2] = a[2]; S[4*G+3] = a[3];
  } else {
    sg4[(G - NGRR) * 512 + tid] = make_uint4(h2u(a[0]), h2u(a[1]), h2u(a[2]), h2u(a[3]));
  }
}
template<int G>
__device__ __forceinline__ uint4 vg_pack(const __half2 (&S)[NSR], const uint4* sg4, unsigned tid) {
  if constexpr (G < NGRR)
    return make_uint4(h2u(S[4*G]), h2u(S[4*G+1]), h2u(S[4*G+2]), h2u(S[4*G+3]));
  else
    return sg4[(G - NGRR) * 512 + tid];
}

// update granule G from staged partner uint4 (elem map e^me); 2 upd2 blocks
template<int G, int me, unsigned cm>
__device__ __forceinline__ void vg_upd(__half2 (&S)[NSR], uint4* sg4, unsigned tid, uint4 pv,
                                       __half2 c0, __half2 c1p, __half2 c1n,
                                       __half2 c2p, __half2 c2n, __half2 c3) {
  const unsigned q[4] = { pv.x, pv.y, pv.z, pv.w };
  __half2 a[4]; vg_load<G>(S, sg4, tid, a);
  constexpr int t0 = popc16(cm & (unsigned)(4*G+0)) & 1;
  constexpr int t1 = popc16(cm & (unsigned)(4*G+1)) & 1;
  constexpr int t2 = popc16(cm & (unsigned)(4*G+2)) & 1;
  constexpr int t3 = popc16(cm & (unsigned)(4*G+3)) & 1;
  upd2(a[0], a[1], u2h(q[0^me]), u2h(q[1^me]),
       c0, t0?c1n:c1p, t1?c1n:c1p, t0?c2n:c2p, t1?c2n:c2p, c3);
  upd2(a[2], a[3], u2h(q[2^me]), u2h(q[3^me]),
       c0, t2?c1n:c1p, t3?c1n:c1p, t2?c2n:c2p, t3?c2n:c2p, c3);
  vg_store<G>(S, sg4, tid, a);
}

// ---------------- generalized gate application ----------------
// j = (tid << 7) | L;  L in [0,128): 104 reg amps + 24 LDS amps.
template<int G>
__device__ __forceinline__ void apply_gate(__half2 (&S)[NSR], unsigned tid,
                                           const uint4* __restrict__ ctabg,
                                           uint4* sg4, uint4* xbuf4) {
  constexpr unsigned m  = TB.gm[G];
  constexpr unsigned c  = TB.gc[G];
  constexpr unsigned mL = m & 127u;   // local-bit part (7 bits)
  constexpr unsigned mT = m >> 7;     // thread-bit part (lane 0..5, wave 6..8)
  constexpr unsigned mW = m >> 13;    // wave part (3 bits)

  const uint4 cc = ctabg[G];
  const unsigned fm = (__popc((c >> 7) & tid) & 1u) ? 0x80008000u : 0u;
  const unsigned c1u = cc.y ^ fm, c2u = cc.z ^ fm;
  const __half2 c0 = u2h(cc.x), c3 = u2h(cc.w);
  const __half2 c1p = u2h(c1u), c1n = u2h(c1u ^ 0x80008000u);
  const __half2 c2p = u2h(c2u), c2n = u2h(c2u ^ 0x80008000u);

  if constexpr (mW == 0u) {
    // ============ in-thread / lane-crossing (generic granule walk) ============
    constexpr int lx = (int)mT;       // 0 -> pure local; else shfl distance
    if constexpr (mL == 0u) {
      // self-position pair across lanes (lx != 0)
      sfor<NG>([&](auto gg) {
        constexpr int g = decltype(gg)::value;
        __half2 a[4]; vg_load<g>(S, sg4, tid, a);
        const __half2 p0 = pget<lx>(a[0]), p1 = pget<lx>(a[1]);
        const __half2 p2 = pget<lx>(a[2]), p3 = pget<lx>(a[3]);
        constexpr int t0 = popc16(c & (unsigned)(4*g+0)) & 1;
        constexpr int t1 = popc16(c & (unsigned)(4*g+1)) & 1;
        constexpr int t2 = popc16(c & (unsigned)(4*g+2)) & 1;
        constexpr int t3 = popc16(c & (unsigned)(4*g+3)) & 1;
        upd2(a[0], a[1], p0, p1, c0, t0?c1n:c1p, t1?c1n:c1p, t0?c2n:c2p, t1?c2n:c2p, c3);
        upd2(a[2], a[3], p2, p3, c0, t2?c1n:c1p, t3?c1n:c1p, t2?c2n:c2p, t3?c2n:c2p, c3);
        vg_store<g>(S, sg4, tid, a);
      });
    } else if constexpr ((mL >> 2) == 0u) {
      // within-granule pairs (mL in 1..3): one upd2 per pair
      constexpr int tb = topbit_pow(mL);
      sfor<NG>([&](auto gg) {
        constexpr int g = decltype(gg)::value;
        __half2 a[4]; vg_load<g>(S, sg4, tid, a);
        sfor<4>([&](auto ee) {
          constexpr int e = decltype(ee)::value;
          if constexpr ((e & tb) == 0) {
            constexpr int e1 = e ^ (int)mL;
            constexpr int t0 = popc16(c & (unsigned)(4*g+e)) & 1;
            constexpr int t1 = popc16(c & (unsigned)(4*g+e1)) & 1;
            const __half2 x0 = a[e], x1 = a[e1];
            upd2(a[e], a[e1], pget<lx>(x1), pget<lx>(x0),
                 c0, t0?c1n:c1p, t1?c1n:c1p, t0?c2n:c2p, t1?c2n:c2p, c3);
          }
        });
        vg_store<g>(S, sg4, tid, a);
      });
    } else {
      // granule pairs (gA, gB = gA ^ hg); reg/LDS/mixed handled by vg_*
      constexpr int hg = (int)(mL >> 2);
      constexpr int tb = topbit_pow((unsigned)hg);
      constexpr int me = (int)(mL & 3u);
      sfor<NG>([&](auto ga_) {
        constexpr int gA = decltype(ga_)::value;
        if constexpr ((gA & tb) == 0) {
          constexpr int gB = gA ^ hg;
          __half2 a[4], b4[4];
          vg_load<gA>(S, sg4, tid, a); vg_load<gB>(S, sg4, tid, b4);
          sfor<4>([&](auto ee) {
            constexpr int e  = decltype(ee)::value;
            constexpr int e2 = e ^ me;
            constexpr int t0 = popc16(c & (unsigned)(4*gA+e)) & 1;
            constexpr int t1 = popc16(c & (unsigned)(4*gB+e2)) & 1;
            const __half2 x0 = a[e], x1 = b4[e2];
            upd2(a[e], b4[e2], pget<lx>(x1), pget<lx>(x0),
                 c0, t0?c1n:c1p, t1?c1n:c1p, t0?c2n:c2p, t1?c2n:c2p, c3);
          });
          vg_store<gA>(S, sg4, tid, a); vg_store<gB>(S, sg4, tid, b4);
        }
      });
    }
  } else {
    // ============ wave-crossing: xbuf rounds (8 slots, stride-9 pad) ============
    const unsigned ptid = tid ^ (unsigned)mT;
    constexpr unsigned hG = mL >> 2;          // granule xor (5 bits)
    constexpr int      me = (int)(mL & 3u);
    if constexpr (hG == 0u) {
      // partner in same granule: 4 rounds of 8 consecutive granules
      sfor<4>([&](auto rr) {
        constexpr int r = decltype(rr)::value;
        sfor<8>([&](auto kk) {
          constexpr int k = decltype(kk)::value;
          xbuf4[tid * 9u + (unsigned)k] = vg_pack<r * 8 + k>(S, sg4, tid);
        });
        __syncthreads();
        sfor<8>([&](auto kk) {
          constexpr int k = decltype(kk)::value;
          const uint4 pv = xbuf4[ptid * 9u + (unsigned)k];
          vg_upd<r * 8 + k, me, c>(S, sg4, tid, pv, c0, c1p, c1n, c2p, c2n, c3);
        });
        __syncthreads();
      });
    } else {
      // granule pairs (gA, gB = gA ^ hG): 4 rounds of 4 pairs
      constexpr int tbG = topbit_pow(hG);
      sfor<4>([&](auto rr) {
        constexpr int r = decltype(rr)::value;
        sfor<4>([&](auto kk) {
          constexpr int k  = decltype(kk)::value;
          constexpr int i  = r * 4 + k;
          constexpr int gA = ((i & ~(tbG - 1)) << 1) | (i & (tbG - 1));
          constexpr int gB = gA ^ (int)hG;
          xbuf4[tid * 9u + (unsigned)k]       = vg_pack<gA>(S, sg4, tid);
          xbuf4[tid * 9u + (unsigned)(4 + k)] = vg_pack<gB>(S, sg4, tid);
        });
        __syncthreads();
        sfor<4>([&](auto kk) {
          constexpr int k  = decltype(kk)::value;
          constexpr int i  = r * 4 + k;
          constexpr int gA = ((i & ~(tbG - 1)) << 1) | (i & (tbG - 1));
          constexpr int gB = gA ^ (int)hG;
          const uint4 pvB = xbuf4[ptid * 9u + (unsigned)(4 + k)];
          const uint4 pvA = xbuf4[ptid * 9u + (unsigned)k];
          vg_upd<gA, me, c>(S, sg4, tid, pvB, c0, c1p, c1n, c2p, c2n, c3);
          vg_upd<gB, me, c>(S, sg4, tid, pvA, c0, c1p, c1n, c2p, c2n, c3);
        });
        __syncthreads();
      });
    }
  }
}

// ---------------- coefficient prekernel (batch-independent) ----------------
__global__ void ctab_build(const float* __restrict__ weight, uint4* __restrict__ ctabg) {
  const int g = (int)threadIdx.x;   // 64 threads
  const int k = g >> 4;             // 0..3 -> layers 2..5
  const int bb = g & 15;
  const int w = 15 - bb;            // wire for this logical bit
  const int base = 48 * (k + 1) + 3 * w;
  float are, aim, bre, bim;
  su2_coeffs(weight[base], weight[base + 1], weight[base + 2], are, aim, bre, bim);
  ctabg[g] = make_uint4(pkh2(are, are), pkh2(-aim, aim),
                        pkh2(-bre, -bre), pkh2(-bim, bim));
}

// ---------------- main kernel ----------------
__global__ __attribute__((amdgpu_flat_work_group_size(512, 512)))
void qcir_kernel(const float* __restrict__ inputs, const float* __restrict__ weight,
                 float* __restrict__ out, const uint4* __restrict__ ctabg) {
  __shared__ uint4  sg4[NGL * 512];  // 48 KB LDS-resident state (amps 104..127)
  __shared__ uint4  xbuf4[512 * 9];  // 73.7 KB exchange staging (stride-9 pad)
  __shared__ float4 itab[16];
  __shared__ float  red[8 * 16];

  const unsigned tid = threadIdx.x;   // 9 bits
  const unsigned b   = blockIdx.x;

  // ---- itab: per-wire (al,be) after encoding + layer 1 ----
  if (tid < 16) {
    const int w = (int)tid;
    const float a = weight[3 * w] + inputs[b * 16 + w];
    float are, aim, bre, bim;
    su2_coeffs(a, weight[3 * w + 1], weight[3 * w + 2], are, aim, bre, bim);
    itab[w] = make_float4(are, aim, bre, bim);
  }
  __syncthreads();

  // ---- init: product state after encoding + layer 1  (A1 = I) ----
  __half2 S[NSR];
  float2 P = make_float2(1.f, 0.f);
#pragma unroll
  for (int p = 7; p <= 15; ++p) {
    const int bit = (int)(tid >> (p - 7)) & 1;
    const float4 t = itab[15 - p];
    P = cmulf(P, bit ? t.z : t.x, bit ? t.w : t.y);
  }
  sfor<16>([&](auto hh) {
    constexpr int h = decltype(hh)::value;        // chunk of 8: L bits 3..6
    float2 ph = P;
    sfor<4>([&](auto qq) {
      constexpr int q   = decltype(qq)::value;
      constexpr int bit = (h >> q) & 1;
      const float4 t = itab[12 - q];
      if constexpr (bit) ph = cmulf(ph, t.z, t.w); else ph = cmulf(ph, t.x, t.y);
    });
    if constexpr (h < 13) {
      sfor<8>([&](auto ll) {
        constexpr int l = decltype(ll)::value;
        float2 pl = ph;
        sfor<3>([&](auto qq) {
          constexpr int q   = decltype(qq)::value;
          constexpr int bit = (l >> q) & 1;
          const float4 t = itab[15 - q];
          if constexpr (bit) pl = cmulf(pl, t.z, t.w); else pl = cmulf(pl, t.x, t.y);
        });
        S[h * 8 + l] = __floats2half2_rn(pl.x, pl.y);
      });
    } else {
      __half2 a0[4], a1[4];
      sfor<8>([&](auto ll) {
        constexpr int l = decltype(ll)::value;
        float2 pl = ph;
        sfor<3>([&](auto qq) {
          constexpr int q   = decltype(qq)::value;
          constexpr int bit = (l >> q) & 1;
          const float4 t = itab[15 - q];
          if constexpr (bit) pl = cmulf(pl, t.z, t.w); else pl = cmulf(pl, t.x, t.y);
        });
        const __half2 v = __floats2half2_rn(pl.x, pl.y);
        if constexpr (l < 4) a0[l] = v; else a1[l - 4] = v;
      });
      // chunk h (h>=13) -> LDS granules 2(h-13), 2(h-13)+1
      sg4[(2 * (h - 13)) * 512 + tid]     = make_uint4(h2u(a0[0]), h2u(a0[1]), h2u(a0[2]), h2u(a0[3]));
      sg4[(2 * (h - 13) + 1) * 512 + tid] = make_uint4(h2u(a1[0]), h2u(a1[1]), h2u(a1[2]), h2u(a1[3]));
    }
  });
  __syncthreads();

  // ---- layers 2..5: 64 generalized gates (rings virtualized) ----
  sfor<64>([&](auto gg) { apply_gate<decltype(gg)::value>(S, tid, ctabg, sg4, xbuf4); });

  // ---- measurement: <Z_w> in 2 passes of 8 outputs ----
  sfor<2>([&](auto hf_) {
    constexpr int hf = decltype(hf_)::value;
    float acc[8];
    sfor<8>([&](auto ww) { acc[decltype(ww)::value] = 0.f; });
    sfor<NSR>([&](auto ll) {
      constexpr int L = decltype(ll)::value;
      const float re = __low2float(S[L]);
      const float im = __high2float(S[L]);
      const float p = re * re + im * im;
      sfor<8>([&](auto w8) {
        constexpr int w = hf * 8 + decltype(w8)::value;
        constexpr int t = popc16(TB.meas[w] & 127u & (unsigned)L) & 1;
        if constexpr (t) acc[decltype(w8)::value] -= p; else acc[decltype(w8)::value] += p;
      });
    });
    sfor<NGL>([&](auto gg) {
      constexpr int g = decltype(gg)::value;
      const uint4 v = sg4[g * 512 + tid];
      const unsigned q[4] = { v.x, v.y, v.z, v.w };
      sfor<4>([&](auto ee) {
        constexpr int e = decltype(ee)::value;
        constexpr int L = NSR + g * 4 + e;
        const __half2 av = u2h(q[e]);
        const float re = __low2float(av);
        const float im = __high2float(av);
        const float p = re * re + im * im;
        sfor<8>([&](auto w8) {
          constexpr int w = hf * 8 + decltype(w8)::value;
          constexpr int t = popc16(TB.meas[w] & 127u & (unsigned)L) & 1;
          if constexpr (t) acc[decltype(w8)::value] -= p; else acc[decltype(w8)::value] += p;
        });
      });
    });
    sfor<8>([&](auto w8) {
      constexpr int w = hf * 8 + decltype(w8)::value;
      const unsigned fw = __popc((TB.meas[w] >> 7) & tid) & 1u;
      float z = fw ? -acc[decltype(w8)::value] : acc[decltype(w8)::value];
#pragma unroll
      for (int d = 1; d < 64; d <<= 1) z += __shfl_xor(z, d, 64);
      if ((tid & 63u) == 0u) red[(tid >> 6) * 16 + w] = z;
    });
  });
  __syncthreads();
  if (tid < 16) {
    float s = 0.f;
#pragma unroll
    for (int v = 0; v < 8; ++v) s += red[v * 16 + tid];
    out[b * 16 + tid] = 4.f * s;
  }
}

// ---------------- launcher ----------------
extern "C" void kernel_launch(void* const* d_in, const int* in_sizes, int n_in,
                              void* d_out, int out_size, void* d_ws, size_t ws_size,
                              hipStream_t stream) {
  const float* inputs = (const float*)d_in[0];   // (B, 16) f32
  const float* weight = (const float*)d_in[1];   // (240,)  f32
  float* out = (float*)d_out;                    // (B, 16) f32
  const int B = in_sizes[0] / 16;
  uint4* ctabg = reinterpret_cast<uint4*>(d_ws); // 1 KB of workspace
  ctab_build<<<1, 64, 0, stream>>>(weight, ctabg);
  qcir_kernel<<<B, 512, 0, stream>>>(inputs, weight, out, ctabg);
}